// Round 5
// baseline (809.525 us; speedup 1.0000x reference)
//
#include <hip/hip_runtime.h>

// ---------------------------------------------------------------------------
// BoTNet attention head on MI355X (gfx950).
// conv1x1+BN+ReLU -> qkv conv -> rel-logit MFMA precompute ->
// flash attention (bf16 MFMA, 2-wave/64q blocks, 32q/wave, split-K=4,
// defer-max, reg-staged K/V, packed-bf16 bias) -> merge ->
// conv1x1(MFMA)+BN+residual+ReLU -> conv1x1(MFMA) head.
// ---------------------------------------------------------------------------

typedef __attribute__((ext_vector_type(4))) float f32x4;
typedef __attribute__((ext_vector_type(8))) short s16x8;
typedef __attribute__((ext_vector_type(4))) unsigned short u16x4;

#define HW_N 4608
#define EPS 1e-5f
#define QSCALE 0.08838834764831845f  // 128^-0.5

__device__ __forceinline__ unsigned short f2bf(float f) {
  unsigned u = __builtin_bit_cast(unsigned, f);
  u += 0x7fffu + ((u >> 16) & 1u);          // round-to-nearest-even
  return (unsigned short)(u >> 16);
}
__device__ __forceinline__ float bf2f(unsigned short s) {
  return __builtin_bit_cast(float, ((unsigned)s) << 16);
}
__device__ __forceinline__ float bwsel(unsigned pk, bool par) {
  // packed (lo=even-tile bias, hi=odd-tile bias) bf16 pair -> float
  return __builtin_bit_cast(float, par ? (pk & 0xffff0000u) : (pk << 16));
}
__device__ __forceinline__ void gload_lds16(const void* g, void* l) {
  __builtin_amdgcn_global_load_lds(g, l, 16, 0, 0);
}

// ---------------------------------------------------------------------------
// conv1: h1[64][4608] = relu(bn(w_in @ x)); K=256  (fp32)
// ---------------------------------------------------------------------------
__global__ __launch_bounds__(256) void conv1_kernel(
    const float* __restrict__ x, const float* __restrict__ w,
    const float* __restrict__ gg, const float* __restrict__ bb,
    const float* __restrict__ mm, const float* __restrict__ vv,
    float* __restrict__ h1)
{
  __shared__ __align__(16) unsigned char smA[16384];
  __shared__ __align__(16) unsigned char smB[16384];
  const int tid = (int)threadIdx.x;
  const int tx = tid & 15, ty = tid >> 4;
  const int p0 = (int)blockIdx.x * 64;
  float acc[4][4] = {};
  for (int ch = 0; ch < 4; ++ch) {
    __syncthreads();
#pragma unroll
    for (int pass = 0; pass < 4; ++pass) {
      int c4 = tid + pass * 256;
      int oc = c4 >> 4, cc4 = c4 & 15;
      f32x4 a = *(const f32x4*)(w + oc * 256 + ch * 64 + cc4 * 4);
#pragma unroll
      for (int k = 0; k < 4; ++k) {
        int cc = cc4 * 4 + k;
        *(float*)(smA + cc * 256 + ((oc * 4) ^ ((cc & 7) << 4))) = a[k];
      }
      int cc = c4 >> 4, pp4 = c4 & 15;
      f32x4 b = *(const f32x4*)(x + (ch * 64 + cc) * HW_N + p0 + pp4 * 4);
      *(f32x4*)(smB + cc * 256 + ((pp4 * 16) ^ ((cc & 7) << 4))) = b;
    }
    __syncthreads();
#pragma unroll 8
    for (int cc = 0; cc < 64; ++cc) {
      f32x4 av = *(const f32x4*)(smA + cc * 256 + ((ty * 16) ^ ((cc & 7) << 4)));
      f32x4 bv = *(const f32x4*)(smB + cc * 256 + ((tx * 16) ^ ((cc & 7) << 4)));
#pragma unroll
      for (int i = 0; i < 4; ++i)
#pragma unroll
        for (int j = 0; j < 4; ++j) acc[i][j] = fmaf(av[i], bv[j], acc[i][j]);
    }
  }
#pragma unroll
  for (int i = 0; i < 4; ++i) {
    int oc = ty * 4 + i;
    float inv = gg[oc] * rsqrtf(vv[oc] + EPS);
    float bia = bb[oc] - mm[oc] * inv;
    f32x4 o;
#pragma unroll
    for (int j = 0; j < 4; ++j) o[j] = fmaxf(acc[i][j] * inv + bia, 0.f);
    *(f32x4*)(h1 + oc * HW_N + p0 + tx * 4) = o;
  }
}

// ---------------------------------------------------------------------------
// convqkv (fp32): qkv = w_qkv @ h1; scatter q(scaled)/k [h][p][128],
// v [h][128][p] bf16.
// ---------------------------------------------------------------------------
__global__ __launch_bounds__(256) void convqkv_kernel(
    const float* __restrict__ h1, const float* __restrict__ w,
    unsigned short* __restrict__ qb, unsigned short* __restrict__ kb,
    unsigned short* __restrict__ vb)
{
  __shared__ __align__(16) unsigned char smA[16384];
  __shared__ __align__(16) unsigned char smB[16384];
  const int tid = (int)threadIdx.x;
  const int tx = tid & 15, ty = tid >> 4;
  const int p0 = (int)blockIdx.x * 64;
  const int o0 = (int)blockIdx.y * 64;
  float acc[4][4] = {};
#pragma unroll
  for (int pass = 0; pass < 4; ++pass) {
    int c4 = tid + pass * 256;
    int oc = c4 >> 4, cc4 = c4 & 15;
    f32x4 a = *(const f32x4*)(w + (o0 + oc) * 64 + cc4 * 4);
#pragma unroll
    for (int k = 0; k < 4; ++k) {
      int cc = cc4 * 4 + k;
      *(float*)(smA + cc * 256 + ((oc * 4) ^ ((cc & 7) << 4))) = a[k];
    }
    int cc = c4 >> 4, pp4 = c4 & 15;
    f32x4 b = *(const f32x4*)(h1 + cc * HW_N + p0 + pp4 * 4);
    *(f32x4*)(smB + cc * 256 + ((pp4 * 16) ^ ((cc & 7) << 4))) = b;
  }
  __syncthreads();
#pragma unroll 8
  for (int cc = 0; cc < 64; ++cc) {
    f32x4 av = *(const f32x4*)(smA + cc * 256 + ((tx * 16) ^ ((cc & 7) << 4)));
    f32x4 bv = *(const f32x4*)(smB + cc * 256 + ((ty * 16) ^ ((cc & 7) << 4)));
#pragma unroll
    for (int i = 0; i < 4; ++i)
#pragma unroll
      for (int j = 0; j < 4; ++j) acc[i][j] = fmaf(av[i], bv[j], acc[i][j]);
  }
  const int chunk = o0 >> 9, head = (o0 >> 7) & 3, dbase = o0 & 127;
  if (chunk == 0) {
#pragma unroll
    for (int j = 0; j < 4; ++j) {
      unsigned short pk[4];
#pragma unroll
      for (int i = 0; i < 4; ++i) pk[i] = f2bf(acc[i][j] * QSCALE);
      *(unsigned long long*)(qb + (head * HW_N + p0 + ty * 4 + j) * 128 + dbase + tx * 4) =
          *(unsigned long long*)pk;
    }
  } else if (chunk == 1) {
#pragma unroll
    for (int j = 0; j < 4; ++j) {
      unsigned short pk[4];
#pragma unroll
      for (int i = 0; i < 4; ++i) pk[i] = f2bf(acc[i][j]);
      *(unsigned long long*)(kb + (head * HW_N + p0 + ty * 4 + j) * 128 + dbase + tx * 4) =
          *(unsigned long long*)pk;
    }
  } else {
#pragma unroll
    for (int i = 0; i < 4; ++i) {
      unsigned short pk[4];
#pragma unroll
      for (int j = 0; j < 4; ++j) pk[j] = f2bf(acc[i][j]);
      *(unsigned long long*)(vb + (head * 128 + dbase + tx * 4 + i) * HW_N + p0 + ty * 4) =
          *(unsigned long long*)pk;
    }
  }
}

// ---------------------------------------------------------------------------
// relpre via MFMA (combined): bx<96 -> mode0 (wq=bx): C[48 hq][96 wk] vs rel_w
//                             bx>=96 -> mode1 (hq=bx-96): C[96 wq][48 hk] vs rel_h
// ---------------------------------------------------------------------------
__global__ __launch_bounds__(256) void relpre_mfma(
    const unsigned short* __restrict__ qb,
    const float* __restrict__ rel_h, const float* __restrict__ rel_w,
    float* __restrict__ RW, float* __restrict__ RH)
{
  __shared__ __align__(16) unsigned char sm[36864];
  int bxr = (int)blockIdx.x;
  const int mode = bxr >= 96;
  const int bx = mode ? bxr - 96 : bxr;
  const int h = (int)blockIdx.y;
  const int tid = (int)threadIdx.x;
  const int wv = tid >> 6, g = (tid >> 4) & 3, c = tid & 15;
  const int NA = mode ? 96 : 48;
  const int NB = mode ? 48 : 96;
  const int TC = NB >> 4;
  const int roff = mode ? (47 - bx) : (95 - bx);
  const float* rel = mode ? rel_h : rel_w;
  float* outp = mode ? RH : RW;
  unsigned char* const smQ = sm;
  unsigned char* const smR = sm + NA * 256;

  for (int ch = tid; ch < (NA + NB) * 16; ch += 256) {
    if (ch < NA * 16) {
      int i = ch >> 4, d8 = ch & 15;
      int p = mode ? (bx * 96 + i) : (i * 96 + bx);
      s16x8 v = *(const s16x8*)(qb + ((size_t)h * HW_N + p) * 128 + d8 * 8);
      *(s16x8*)(smQ + i * 256 + ((d8 * 16) ^ ((i & 7) << 4))) = v;
    } else {
      int c2 = ch - NA * 16;
      int j = c2 >> 4, d8 = c2 & 15;
      const float* rp = rel + (roff + j) * 128 + d8 * 8;
      f32x4 r0 = *(const f32x4*)(rp);
      f32x4 r1 = *(const f32x4*)(rp + 4);
      s16x8 pk;
#pragma unroll
      for (int e = 0; e < 4; ++e) {
        pk[e] = (short)f2bf(r0[e]);
        pk[4 + e] = (short)f2bf(r1[e]);
      }
      *(s16x8*)(smR + j * 256 + ((d8 * 16) ^ ((j & 7) << 4))) = pk;
    }
  }
  __syncthreads();

  const int swzc = (c & 7) << 4;
  for (int tile = wv; tile < 18; tile += 4) {
    const int tr = tile / TC, tc = tile % TC;
    f32x4 acc = {};
#pragma unroll
    for (int kk = 0; kk < 4; ++kk) {
      const int koff = (kk * 64 + g * 16) ^ swzc;
      s16x8 a = *(const s16x8*)(smQ + (tr * 16 + c) * 256 + koff);
      s16x8 b = *(const s16x8*)(smR + (tc * 16 + c) * 256 + koff);
      acc = __builtin_amdgcn_mfma_f32_16x16x32_bf16(a, b, acc, 0, 0, 0);
    }
#pragma unroll
    for (int j = 0; j < 4; ++j) {
      int i = tr * 16 + g * 4 + j;
      int n = tc * 16 + c;
      if (mode == 0)
        outp[((size_t)h * HW_N + i * 96 + bx) * 96 + n] = acc[j];
      else
        outp[((size_t)h * HW_N + bx * 96 + i) * 48 + n] = acc[j];
    }
  }
}

// ---------------------------------------------------------------------------
// flash attention v4. grid (72,4,4): 16 (h,kh) groups x 72 q-tiles (64 q).
// block 128 = 2 waves x 32 queries. 48-key tiles (image half-rows).
// Reg-staged K+V (single-buffer LDS, prefetch during compute), split-K=4,
// defer-max THR=8, packed-bf16 RW bias, bf16 Opart.
// ---------------------------------------------------------------------------
__global__ __launch_bounds__(128, 2) void attn_kernel(
    const unsigned short* __restrict__ qb,
    const unsigned short* __restrict__ kbuf,
    const unsigned short* __restrict__ vbuf,
    const float* __restrict__ RW,
    const float* __restrict__ RH,
    unsigned short* __restrict__ Opart,
    float* __restrict__ mlbuf)
{
  __shared__ __align__(16) unsigned char sm[36864];
  unsigned char* const smK = sm;          // [48 keys][128 d] bf16, swz (row&7)<<4
  unsigned char* const smV = sm + 12288;  // [128 d][64 slots] bf16, swz (d&7)<<4
  unsigned char* const smP = sm + 28672;  // [64 q][64 slots] bf16, swz (q&7)<<4

  const int tid = (int)threadIdx.x;
  const int wv = tid >> 6;
  const int g = (tid >> 4) & 3;
  const int c = tid & 15;
  const int swzc = (c & 7) << 4;

  int lin = (int)blockIdx.x + 72 * ((int)blockIdx.y + 4 * (int)blockIdx.z);
  const int grp = lin & 15, qt = lin >> 4;
  const int h = grp & 3, kh = grp >> 2;

  const int qbaseW = qt * 64 + wv * 32;
  const int pb = (kh * 4 + h) * HW_N;

  {  // zero smP (8KB) and smV pad slots
    s16x8 z = {};
#pragma unroll
    for (int i = 0; i < 4; ++i) *(s16x8*)(smP + (tid + i * 128) * 16) = z;
#pragma unroll
    for (int i = 0; i < 2; ++i) {
      int idx = tid + i * 128;
      int d = idx >> 1, k6 = 6 + (idx & 1);
      *(s16x8*)(smV + d * 128 + ((k6 * 16) ^ ((d & 7) << 4))) = z;
    }
  }

  // Q fragments
  s16x8 aq[2][4];
#pragma unroll
  for (int u = 0; u < 2; ++u) {
    const unsigned short* qrow =
        qb + ((size_t)h * HW_N + qbaseW + u * 16 + c) * 128 + g * 8;
#pragma unroll
    for (int kk = 0; kk < 4; ++kk) aq[u][kk] = *(const s16x8*)(qrow + kk * 32);
  }

  // RW bias packed bf16 (lo=even-parity, hi=odd-parity); RH fp32 via shfl
  unsigned bw[3][2][4];
  float rh_pre[2][4];
#pragma unroll
  for (int u = 0; u < 2; ++u)
#pragma unroll
    for (int r = 0; r < 4; ++r) {
      const int q = qbaseW + u * 16 + g * 4 + r;
      const float* rwrow = RW + ((size_t)h * HW_N + q) * 96 + c;
#pragma unroll
      for (int kb = 0; kb < 3; ++kb) {
        unsigned lo = f2bf(rwrow[kb * 16]);
        unsigned hi = f2bf(rwrow[48 + kb * 16]);
        bw[kb][u][r] = lo | (hi << 16);
      }
      rh_pre[u][r] = (c < 12) ? RH[((size_t)h * HW_N + q) * 48 + kh * 12 + c] : 0.f;
    }

  f32x4 o[2][8];
#pragma unroll
  for (int u = 0; u < 2; ++u)
#pragma unroll
    for (int cb = 0; cb < 8; ++cb) o[u][cb] = {};
  float mrun[2][4], lrun[2][4];
#pragma unroll
  for (int u = 0; u < 2; ++u)
#pragma unroll
    for (int r = 0; r < 4; ++r) { mrun[u][r] = -1e30f; lrun[u][r] = 0.f; }

  const unsigned short* kbase = kbuf + ((size_t)h * HW_N + kh * 1152) * 128;
  const unsigned short* vbase = vbuf + (size_t)h * 128 * HW_N + kh * 1152;

  // staging indices (6 chunks of 16B each for K and V)
  int krow[6], kchk[6], vd[6], vk[6];
#pragma unroll
  for (int j = 0; j < 6; ++j) {
    int idx = tid + j * 128;
    krow[j] = idx >> 4; kchk[j] = idx & 15;
    vd[j] = idx / 6;    vk[j] = idx % 6;
  }

  s16x8 sK[6], sV[6];
#pragma unroll
  for (int j = 0; j < 6; ++j) {  // prologue: prefetch tile 0
    sK[j] = *(const s16x8*)(kbase + (size_t)krow[j] * 128 + kchk[j] * 8);
    sV[j] = *(const s16x8*)(vbase + (size_t)vd[j] * HW_N + vk[j] * 8);
  }

  for (int t = 0; t < 24; ++t) {
    __syncthreads();  // all waves done reading previous tile
#pragma unroll
    for (int j = 0; j < 6; ++j) {
      *(s16x8*)(smK + krow[j] * 256 + ((kchk[j] * 16) ^ ((krow[j] & 7) << 4))) = sK[j];
      *(s16x8*)(smV + vd[j] * 128 + ((vk[j] * 16) ^ ((vd[j] & 7) << 4))) = sV[j];
    }
    float rh_[2][4];
#pragma unroll
    for (int u = 0; u < 2; ++u)
#pragma unroll
      for (int r = 0; r < 4; ++r) rh_[u][r] = __shfl(rh_pre[u][r], t >> 1, 16);
    __syncthreads();  // staged tile visible
    if (t < 23) {     // prefetch t+1 (drains one full compute phase later)
      const int j0n = (t + 1) * 48;
#pragma unroll
      for (int j = 0; j < 6; ++j) {
        sK[j] = *(const s16x8*)(kbase + (size_t)(j0n + krow[j]) * 128 + kchk[j] * 8);
        sV[j] = *(const s16x8*)(vbase + (size_t)vd[j] * HW_N + j0n + vk[j] * 8);
      }
    }

    // ---- S = Q K^T (32q x 48k per wave) ----
    f32x4 s[2][3];
#pragma unroll
    for (int u = 0; u < 2; ++u)
#pragma unroll
      for (int kb = 0; kb < 3; ++kb) s[u][kb] = {};
    __builtin_amdgcn_s_setprio(1);
#pragma unroll
    for (int kk = 0; kk < 4; ++kk) {
      const int inr = (kk * 64 + g * 16) ^ swzc;
      s16x8 b0 = *(const s16x8*)(smK + c * 256 + inr);
      s16x8 b1 = *(const s16x8*)(smK + (16 + c) * 256 + inr);
      s16x8 b2 = *(const s16x8*)(smK + (32 + c) * 256 + inr);
#pragma unroll
      for (int u = 0; u < 2; ++u) {
        s[u][0] = __builtin_amdgcn_mfma_f32_16x16x32_bf16(aq[u][kk], b0, s[u][0], 0, 0, 0);
        s[u][1] = __builtin_amdgcn_mfma_f32_16x16x32_bf16(aq[u][kk], b1, s[u][1], 0, 0, 0);
        s[u][2] = __builtin_amdgcn_mfma_f32_16x16x32_bf16(aq[u][kk], b2, s[u][2], 0, 0, 0);
      }
    }
    __builtin_amdgcn_s_setprio(0);

    // ---- bias + online softmax (defer-max THR=8) ----
    const bool par = (t & 1) != 0;
    float tm3[2][4];
    int need = 0;
#pragma unroll
    for (int u = 0; u < 2; ++u)
#pragma unroll
      for (int r = 0; r < 4; ++r) {
        float x0 = s[u][0][r] + bwsel(bw[0][u][r], par) + rh_[u][r];
        float x1 = s[u][1][r] + bwsel(bw[1][u][r], par) + rh_[u][r];
        float x2 = s[u][2][r] + bwsel(bw[2][u][r], par) + rh_[u][r];
        s[u][0][r] = x0; s[u][1][r] = x1; s[u][2][r] = x2;
        tm3[u][r] = fmaxf(fmaxf(x0, x1), x2);
        need |= (tm3[u][r] > mrun[u][r] + 8.f);
      }
    if (__any(need)) {
#pragma unroll
      for (int u = 0; u < 2; ++u)
#pragma unroll
        for (int r = 0; r < 4; ++r) {
          float tg = tm3[u][r];
          tg = fmaxf(tg, __shfl_xor(tg, 1, 16));
          tg = fmaxf(tg, __shfl_xor(tg, 2, 16));
          tg = fmaxf(tg, __shfl_xor(tg, 4, 16));
          tg = fmaxf(tg, __shfl_xor(tg, 8, 16));
          float mn = fmaxf(mrun[u][r], tg);
          float fac = __expf(mrun[u][r] - mn);
          mrun[u][r] = mn;
          lrun[u][r] *= fac;
#pragma unroll
          for (int cb = 0; cb < 8; ++cb) o[u][cb][r] *= fac;
        }
    }
#pragma unroll
    for (int u = 0; u < 2; ++u)
#pragma unroll
      for (int r = 0; r < 4; ++r) {
        float p0_ = __expf(s[u][0][r] - mrun[u][r]);
        float p1_ = __expf(s[u][1][r] - mrun[u][r]);
        float p2_ = __expf(s[u][2][r] - mrun[u][r]);
        lrun[u][r] += p0_ + p1_ + p2_;
        const int row = wv * 32 + u * 16 + g * 4 + r;
        unsigned char* prow = smP + row * 128;
        const int sw = (row & 7) << 4;
        *(unsigned short*)(prow + ((c * 2) ^ sw)) = f2bf(p0_);
        *(unsigned short*)(prow + ((32 + c * 2) ^ sw)) = f2bf(p1_);
        *(unsigned short*)(prow + ((64 + c * 2) ^ sw)) = f2bf(p2_);
      }

    // ---- O += P V ----
    s16x8 pa[2][2];
#pragma unroll
    for (int u = 0; u < 2; ++u)
#pragma unroll
      for (int ks = 0; ks < 2; ++ks)
        pa[u][ks] = *(const s16x8*)(smP + (wv * 32 + u * 16 + c) * 128 +
                                    ((ks * 64 + g * 16) ^ swzc));
    __builtin_amdgcn_s_setprio(1);
#pragma unroll
    for (int ks = 0; ks < 2; ++ks)
#pragma unroll
      for (int cb = 0; cb < 8; ++cb) {
        s16x8 v = *(const s16x8*)(smV + (cb * 16 + c) * 128 + ((ks * 64 + g * 16) ^ swzc));
        o[0][cb] = __builtin_amdgcn_mfma_f32_16x16x32_bf16(pa[0][ks], v, o[0][cb], 0, 0, 0);
        o[1][cb] = __builtin_amdgcn_mfma_f32_16x16x32_bf16(pa[1][ks], v, o[1][cb], 0, 0, 0);
      }
    __builtin_amdgcn_s_setprio(0);
  }

  // final per-row l reduce across the 16-lane group
#pragma unroll
  for (int u = 0; u < 2; ++u)
#pragma unroll
    for (int r = 0; r < 4; ++r) {
      lrun[u][r] += __shfl_xor(lrun[u][r], 1, 16);
      lrun[u][r] += __shfl_xor(lrun[u][r], 2, 16);
      lrun[u][r] += __shfl_xor(lrun[u][r], 4, 16);
      lrun[u][r] += __shfl_xor(lrun[u][r], 8, 16);
    }

  // coalesced Opart store via per-wave LDS transpose (own 4KB region of smP)
  const int l = tid & 63;
#pragma unroll
  for (int u = 0; u < 2; ++u) {
#pragma unroll
    for (int cb = 0; cb < 8; ++cb)
#pragma unroll
      for (int r = 0; r < 4; ++r) {
        const int row = g * 4 + r;
        *(unsigned short*)(smP + wv * 4096 + row * 256 +
                           (((cb * 16 + c) * 2) ^ ((row & 7) << 4))) = f2bf(o[u][cb][r]);
      }
#pragma unroll
    for (int j = 0; j < 4; ++j) {
      const int row = j * 4 + (l >> 4);
      const int off = (l & 15) * 16;
      s16x8 vd16 = *(const s16x8*)(smP + wv * 4096 + row * 256 + (off ^ ((row & 7) << 4)));
      const int p = qbaseW + u * 16 + row;
      *(s16x8*)((char*)Opart + (size_t)(pb + p) * 256 + off) = vd16;
    }
  }
  if (c == 0) {
#pragma unroll
    for (int u = 0; u < 2; ++u)
#pragma unroll
      for (int r = 0; r < 4; ++r) {
        const int p = qbaseW + u * 16 + g * 4 + r;
        mlbuf[((size_t)pb + p) * 2 + 0] = mrun[u][r];
        mlbuf[((size_t)pb + p) * 2 + 1] = lrun[u][r];
      }
  }
}

// ---------------------------------------------------------------------------
// merge 4 split-K partials -> oatt[p][512] bf16 (p-major)
// ---------------------------------------------------------------------------
__global__ __launch_bounds__(256) void merge_kernel(
    const unsigned short* __restrict__ Opart, const float* __restrict__ mlbuf,
    unsigned short* __restrict__ oatt)
{
  int idx = (int)blockIdx.x * 256 + (int)threadIdx.x;  // 4*4608*32
  int d4 = idx & 31;
  int rest = idx >> 5;
  int p = rest % HW_N;
  int h = rest / HW_N;
  float m[4], lv[4];
#pragma unroll
  for (int s = 0; s < 4; ++s) {
    int ip = (s * 4 + h) * HW_N + p;
    m[s] = mlbuf[(size_t)ip * 2];
    lv[s] = mlbuf[(size_t)ip * 2 + 1];
  }
  float M = fmaxf(fmaxf(m[0], m[1]), fmaxf(m[2], m[3]));
  float a[4], den = 0.f;
#pragma unroll
  for (int s = 0; s < 4; ++s) { a[s] = __expf(m[s] - M); den += a[s] * lv[s]; }
  float rd = 1.f / den;
  f32x4 acc = {};
#pragma unroll
  for (int s = 0; s < 4; ++s) {
    int ip = (s * 4 + h) * HW_N + p;
    u16x4 ov = *(const u16x4*)(Opart + (size_t)ip * 128 + d4 * 4);
#pragma unroll
    for (int j = 0; j < 4; ++j) acc[j] = fmaf(a[s], bf2f(ov[j]), acc[j]);
  }
  u16x4 res;
#pragma unroll
  for (int j = 0; j < 4; ++j) res[j] = f2bf(acc[j] * rd);
  *(u16x4*)(oatt + (size_t)p * 512 + h * 128 + d4 * 4) = res;
}

// ---------------------------------------------------------------------------
// convout (MFMA): fm[p][256] bf16 = relu(bn(w_out @ oatt^T) + x); K=512
// grid (36, 4): C tile [64 oc][128 p]
// ---------------------------------------------------------------------------
__global__ __launch_bounds__(256) void convout_kernel(
    const unsigned short* __restrict__ oatt, const float* __restrict__ w,
    const float* __restrict__ gg, const float* __restrict__ bb,
    const float* __restrict__ mm, const float* __restrict__ vv,
    const float* __restrict__ x, unsigned short* __restrict__ fm)
{
  __shared__ __align__(16) unsigned char smA[8192];   // [64 oc][64 cc] bf16 swz
  __shared__ __align__(16) unsigned char smB[16384];  // [128 p][64 cc] bf16 swz
  const int tid = (int)threadIdx.x;
  const int wv = tid >> 6, g = (tid >> 4) & 3, c = tid & 15;
  const int p0 = (int)blockIdx.x * 128;
  const int o0 = (int)blockIdx.y * 64;
  const int swzc = (c & 7) << 4;
  const int aoc = tid >> 2, aq4 = tid & 3;
  const int brow = tid >> 3, bcol = (tid & 7) * 16;
  f32x4 acc[8];
#pragma unroll
  for (int cb = 0; cb < 8; ++cb) acc[cb] = {};

  for (int ch = 0; ch < 8; ++ch) {
    __syncthreads();
#pragma unroll
    for (int i = 0; i < 4; ++i)
      gload_lds16((const char*)oatt + (size_t)(p0 + i * 32 + brow) * 1024 + ch * 128 +
                      (bcol ^ ((brow & 7) << 4)),
                  smB + i * 4096 + wv * 1024);
    {
      const float* wp = w + (size_t)(o0 + aoc) * 512 + ch * 64 + aq4 * 16;
      f32x4 a0 = *(const f32x4*)(wp);
      f32x4 a1 = *(const f32x4*)(wp + 4);
      f32x4 a2 = *(const f32x4*)(wp + 8);
      f32x4 a3 = *(const f32x4*)(wp + 12);
      s16x8 w0, w1;
#pragma unroll
      for (int e = 0; e < 4; ++e) {
        w0[e] = (short)f2bf(a0[e]); w0[4 + e] = (short)f2bf(a1[e]);
        w1[e] = (short)f2bf(a2[e]); w1[4 + e] = (short)f2bf(a3[e]);
      }
      *(s16x8*)(smA + aoc * 128 + ((aq4 * 32) ^ ((aoc & 7) << 4))) = w0;
      *(s16x8*)(smA + aoc * 128 + ((aq4 * 32 + 16) ^ ((aoc & 7) << 4))) = w1;
    }
    __syncthreads();
#pragma unroll
    for (int kk = 0; kk < 2; ++kk) {
      s16x8 a = *(const s16x8*)(smA + (wv * 16 + c) * 128 + ((kk * 64 + g * 16) ^ swzc));
#pragma unroll
      for (int cb = 0; cb < 8; ++cb) {
        s16x8 b = *(const s16x8*)(smB + (cb * 16 + c) * 128 + ((kk * 64 + g * 16) ^ swzc));
        acc[cb] = __builtin_amdgcn_mfma_f32_16x16x32_bf16(a, b, acc[cb], 0, 0, 0);
      }
    }
  }

  __syncthreads();
  float inv[4], bia[4];
#pragma unroll
  for (int r = 0; r < 4; ++r) {
    int oc = o0 + wv * 16 + g * 4 + r;
    inv[r] = gg[oc] * rsqrtf(vv[oc] + EPS);
    bia[r] = bb[oc] - mm[oc] * inv[r];
  }
#pragma unroll
  for (int cb = 0; cb < 8; ++cb)
#pragma unroll
    for (int r = 0; r < 4; ++r) {
      int oc = o0 + wv * 16 + g * 4 + r;
      int p = p0 + cb * 16 + c;
      float v = fmaxf(acc[cb][r] * inv[r] + bia[r] + x[(size_t)oc * HW_N + p], 0.f);
      *(unsigned short*)(smB + (cb * 16 + c) * 128 +
                         (((wv * 16 + g * 4 + r) * 2) ^ swzc)) = f2bf(v);
    }
  __syncthreads();
#pragma unroll
  for (int i = 0; i < 4; ++i) {
    int row = i * 32 + brow;
    s16x8 vd = *(const s16x8*)(smB + row * 128 + (bcol ^ ((row & 7) << 4)));
    *(s16x8*)((char*)fm + (size_t)(p0 + row) * 512 + o0 * 2 + bcol) = vd;
  }
}

// ---------------------------------------------------------------------------
// convhead (MFMA): out[19][4608] = w_head @ fm^T + b_head; K=256. grid 36.
// ---------------------------------------------------------------------------
__global__ __launch_bounds__(256) void convhead_kernel(
    const unsigned short* __restrict__ fm, const float* __restrict__ w,
    const float* __restrict__ bh, float* __restrict__ outp)
{
  __shared__ __align__(16) unsigned char smA[4096];   // [32 oc][64 cc] bf16 swz
  __shared__ __align__(16) unsigned char smB[16384];  // [128 p][64 cc] bf16 swz
  const int tid = (int)threadIdx.x;
  const int wv = tid >> 6, g = (tid >> 4) & 3, c = tid & 15;
  const int p0 = (int)blockIdx.x * 128;
  const int swzc = (c & 7) << 4;
  const int aoc = tid >> 3, aq8 = tid & 7;
  const int brow = tid >> 3, bcol = (tid & 7) * 16;
  f32x4 acc[2][2];
#pragma unroll
  for (int u = 0; u < 2; ++u)
#pragma unroll
    for (int cbi = 0; cbi < 2; ++cbi) acc[u][cbi] = {};

  for (int ch = 0; ch < 4; ++ch) {
    __syncthreads();
#pragma unroll
    for (int i = 0; i < 4; ++i)
      gload_lds16((const char*)fm + (size_t)(p0 + i * 32 + brow) * 512 + ch * 128 +
                      (bcol ^ ((brow & 7) << 4)),
                  smB + i * 4096 + wv * 1024);
    {
      s16x8 w0 = {};
      if (aoc < 19) {
        const float* wp = w + (size_t)aoc * 256 + ch * 64 + aq8 * 8;
        f32x4 a0 = *(const f32x4*)(wp);
        f32x4 a1 = *(const f32x4*)(wp + 4);
#pragma unroll
        for (int e = 0; e < 4; ++e) {
          w0[e] = (short)f2bf(a0[e]);
          w0[4 + e] = (short)f2bf(a1[e]);
        }
      }
      *(s16x8*)(smA + aoc * 128 + ((aq8 * 16) ^ ((aoc & 7) << 4))) = w0;
    }
    __syncthreads();
#pragma unroll
    for (int kk = 0; kk < 2; ++kk) {
      s16x8 a0 = *(const s16x8*)(smA + c * 128 + ((kk * 64 + g * 16) ^ swzc));
      s16x8 a1 = *(const s16x8*)(smA + (16 + c) * 128 + ((kk * 64 + g * 16) ^ swzc));
#pragma unroll
      for (int cbi = 0; cbi < 2; ++cbi) {
        int cb = wv * 2 + cbi;
        s16x8 b = *(const s16x8*)(smB + (cb * 16 + c) * 128 + ((kk * 64 + g * 16) ^ swzc));
        acc[0][cbi] = __builtin_amdgcn_mfma_f32_16x16x32_bf16(a0, b, acc[0][cbi], 0, 0, 0);
        acc[1][cbi] = __builtin_amdgcn_mfma_f32_16x16x32_bf16(a1, b, acc[1][cbi], 0, 0, 0);
      }
    }
  }
#pragma unroll
  for (int u = 0; u < 2; ++u)
#pragma unroll
    for (int cbi = 0; cbi < 2; ++cbi)
#pragma unroll
      for (int r = 0; r < 4; ++r) {
        int oc = u * 16 + g * 4 + r;
        if (oc < 19) {
          int p = p0 + (wv * 2 + cbi) * 16 + c;
          outp[(size_t)oc * HW_N + p] = acc[u][cbi][r] + bh[oc];
        }
      }
}

// ---------------------------------------------------------------------------
extern "C" void kernel_launch(void* const* d_in, const int* in_sizes, int n_in,
                              void* d_out, int out_size, void* d_ws, size_t ws_size,
                              hipStream_t stream)
{
  const float* x     = (const float*)d_in[0];
  const float* w_in  = (const float*)d_in[1];
  const float* bn1_g = (const float*)d_in[2];
  const float* bn1_b = (const float*)d_in[3];
  const float* bn1_m = (const float*)d_in[4];
  const float* bn1_v = (const float*)d_in[5];
  const float* w_qkv = (const float*)d_in[6];
  const float* rel_h = (const float*)d_in[7];
  const float* rel_w = (const float*)d_in[8];
  const float* w_out = (const float*)d_in[9];
  const float* bn2_g = (const float*)d_in[10];
  const float* bn2_b = (const float*)d_in[11];
  const float* bn2_m = (const float*)d_in[12];
  const float* bn2_v = (const float*)d_in[13];
  const float* w_hd  = (const float*)d_in[14];
  const float* b_hd  = (const float*)d_in[15];

  char* ws = (char*)d_ws;
  float*          h1    = (float*)(ws + 0);                   // 1,179,648 B
  float*          mlb   = (float*)(ws + 0);                   // 589,824 B (h1 dead)
  unsigned short* qb    = (unsigned short*)(ws + 1179648);    // 4,718,592 B
  unsigned short* kb    = (unsigned short*)(ws + 5898240);    // 4,718,592 B
  unsigned short* vb    = (unsigned short*)(ws + 10616832);   // 4,718,592 B
  float*          RW    = (float*)(ws + 15335424);            // 7,077,888 B
  float*          RH    = (float*)(ws + 22413312);            // 3,538,944 B
  unsigned short* Opart = (unsigned short*)(ws + 25952256);   // 18,874,368 B
  unsigned short* oatt  = (unsigned short*)(ws + 44826624);   // 4,718,592 B (bf16)
  unsigned short* fm    = (unsigned short*)(ws + 49545216);   // 2,359,296 B (bf16)

  conv1_kernel<<<72, 256, 0, stream>>>(x, w_in, bn1_g, bn1_b, bn1_m, bn1_v, h1);
  convqkv_kernel<<<dim3(72, 24), 256, 0, stream>>>(h1, w_qkv, qb, kb, vb);
  relpre_mfma<<<dim3(144, 4), 256, 0, stream>>>(qb, rel_h, rel_w, RW, RH);
  attn_kernel<<<dim3(72, 4, 4), 128, 0, stream>>>(qb, kb, vb, RW, RH, Opart, mlb);
  merge_kernel<<<2304, 256, 0, stream>>>(Opart, mlb, oatt);
  convout_kernel<<<dim3(36, 4), 256, 0, stream>>>(oatt, w_out, bn2_g, bn2_b, bn2_m,
                                                  bn2_v, x, fm);
  convhead_kernel<<<36, 256, 0, stream>>>(fm, w_hd, b_hd, (float*)d_out);
}

// Round 6
// 249.193 us; speedup vs baseline: 3.2486x; 3.2486x over previous
//
#include <hip/hip_runtime.h>

// ---------------------------------------------------------------------------
// BoTNet attention head on MI355X (gfx950).
// conv1x1+BN+ReLU -> qkv conv -> rel-logit MFMA precompute ->
// flash attention (bf16 MFMA, 4 waves x 16q, split-K=6, defer-max) -> merge ->
// conv1x1(MFMA)+BN+residual+ReLU -> conv1x1(MFMA) head.
// attn is the proven round-2 body (VGPR 92, no spill) + split-K=6 + setprio.
// ---------------------------------------------------------------------------

typedef __attribute__((ext_vector_type(4))) float f32x4;
typedef __attribute__((ext_vector_type(8))) short s16x8;
typedef __attribute__((ext_vector_type(4))) unsigned short u16x4;

#define HW_N 4608
#define EPS 1e-5f
#define QSCALE 0.08838834764831845f  // 128^-0.5

__device__ __forceinline__ unsigned short f2bf(float f) {
  unsigned u = __builtin_bit_cast(unsigned, f);
  u += 0x7fffu + ((u >> 16) & 1u);          // round-to-nearest-even
  return (unsigned short)(u >> 16);
}
__device__ __forceinline__ float bf2f(unsigned short s) {
  return __builtin_bit_cast(float, ((unsigned)s) << 16);
}
__device__ __forceinline__ void gload_lds16(const void* g, void* l) {
  __builtin_amdgcn_global_load_lds(g, l, 16, 0, 0);
}

// ---------------------------------------------------------------------------
// conv1: h1[64][4608] = relu(bn(w_in @ x)); K=256  (fp32)
// ---------------------------------------------------------------------------
__global__ __launch_bounds__(256) void conv1_kernel(
    const float* __restrict__ x, const float* __restrict__ w,
    const float* __restrict__ gg, const float* __restrict__ bb,
    const float* __restrict__ mm, const float* __restrict__ vv,
    float* __restrict__ h1)
{
  __shared__ __align__(16) unsigned char smA[16384];
  __shared__ __align__(16) unsigned char smB[16384];
  const int tid = (int)threadIdx.x;
  const int tx = tid & 15, ty = tid >> 4;
  const int p0 = (int)blockIdx.x * 64;
  float acc[4][4] = {};
  for (int ch = 0; ch < 4; ++ch) {
    __syncthreads();
#pragma unroll
    for (int pass = 0; pass < 4; ++pass) {
      int c4 = tid + pass * 256;
      int oc = c4 >> 4, cc4 = c4 & 15;
      f32x4 a = *(const f32x4*)(w + oc * 256 + ch * 64 + cc4 * 4);
#pragma unroll
      for (int k = 0; k < 4; ++k) {
        int cc = cc4 * 4 + k;
        *(float*)(smA + cc * 256 + ((oc * 4) ^ ((cc & 7) << 4))) = a[k];
      }
      int cc = c4 >> 4, pp4 = c4 & 15;
      f32x4 b = *(const f32x4*)(x + (ch * 64 + cc) * HW_N + p0 + pp4 * 4);
      *(f32x4*)(smB + cc * 256 + ((pp4 * 16) ^ ((cc & 7) << 4))) = b;
    }
    __syncthreads();
#pragma unroll 8
    for (int cc = 0; cc < 64; ++cc) {
      f32x4 av = *(const f32x4*)(smA + cc * 256 + ((ty * 16) ^ ((cc & 7) << 4)));
      f32x4 bv = *(const f32x4*)(smB + cc * 256 + ((tx * 16) ^ ((cc & 7) << 4)));
#pragma unroll
      for (int i = 0; i < 4; ++i)
#pragma unroll
        for (int j = 0; j < 4; ++j) acc[i][j] = fmaf(av[i], bv[j], acc[i][j]);
    }
  }
#pragma unroll
  for (int i = 0; i < 4; ++i) {
    int oc = ty * 4 + i;
    float inv = gg[oc] * rsqrtf(vv[oc] + EPS);
    float bia = bb[oc] - mm[oc] * inv;
    f32x4 o;
#pragma unroll
    for (int j = 0; j < 4; ++j) o[j] = fmaxf(acc[i][j] * inv + bia, 0.f);
    *(f32x4*)(h1 + oc * HW_N + p0 + tx * 4) = o;
  }
}

// ---------------------------------------------------------------------------
// convqkv (fp32): qkv = w_qkv @ h1; scatter q(scaled)/k [h][p][128],
// v [h][128][p] bf16.
// ---------------------------------------------------------------------------
__global__ __launch_bounds__(256) void convqkv_kernel(
    const float* __restrict__ h1, const float* __restrict__ w,
    unsigned short* __restrict__ qb, unsigned short* __restrict__ kb,
    unsigned short* __restrict__ vb)
{
  __shared__ __align__(16) unsigned char smA[16384];
  __shared__ __align__(16) unsigned char smB[16384];
  const int tid = (int)threadIdx.x;
  const int tx = tid & 15, ty = tid >> 4;
  const int p0 = (int)blockIdx.x * 64;
  const int o0 = (int)blockIdx.y * 64;
  float acc[4][4] = {};
#pragma unroll
  for (int pass = 0; pass < 4; ++pass) {
    int c4 = tid + pass * 256;
    int oc = c4 >> 4, cc4 = c4 & 15;
    f32x4 a = *(const f32x4*)(w + (o0 + oc) * 64 + cc4 * 4);
#pragma unroll
    for (int k = 0; k < 4; ++k) {
      int cc = cc4 * 4 + k;
      *(float*)(smA + cc * 256 + ((oc * 4) ^ ((cc & 7) << 4))) = a[k];
    }
    int cc = c4 >> 4, pp4 = c4 & 15;
    f32x4 b = *(const f32x4*)(h1 + cc * HW_N + p0 + pp4 * 4);
    *(f32x4*)(smB + cc * 256 + ((pp4 * 16) ^ ((cc & 7) << 4))) = b;
  }
  __syncthreads();
#pragma unroll 8
  for (int cc = 0; cc < 64; ++cc) {
    f32x4 av = *(const f32x4*)(smA + cc * 256 + ((tx * 16) ^ ((cc & 7) << 4)));
    f32x4 bv = *(const f32x4*)(smB + cc * 256 + ((ty * 16) ^ ((cc & 7) << 4)));
#pragma unroll
    for (int i = 0; i < 4; ++i)
#pragma unroll
      for (int j = 0; j < 4; ++j) acc[i][j] = fmaf(av[i], bv[j], acc[i][j]);
  }
  const int chunk = o0 >> 9, head = (o0 >> 7) & 3, dbase = o0 & 127;
  if (chunk == 0) {
#pragma unroll
    for (int j = 0; j < 4; ++j) {
      unsigned short pk[4];
#pragma unroll
      for (int i = 0; i < 4; ++i) pk[i] = f2bf(acc[i][j] * QSCALE);
      *(unsigned long long*)(qb + (head * HW_N + p0 + ty * 4 + j) * 128 + dbase + tx * 4) =
          *(unsigned long long*)pk;
    }
  } else if (chunk == 1) {
#pragma unroll
    for (int j = 0; j < 4; ++j) {
      unsigned short pk[4];
#pragma unroll
      for (int i = 0; i < 4; ++i) pk[i] = f2bf(acc[i][j]);
      *(unsigned long long*)(kb + (head * HW_N + p0 + ty * 4 + j) * 128 + dbase + tx * 4) =
          *(unsigned long long*)pk;
    }
  } else {
#pragma unroll
    for (int i = 0; i < 4; ++i) {
      unsigned short pk[4];
#pragma unroll
      for (int j = 0; j < 4; ++j) pk[j] = f2bf(acc[i][j]);
      *(unsigned long long*)(vb + (head * 128 + dbase + tx * 4 + i) * HW_N + p0 + ty * 4) =
          *(unsigned long long*)pk;
    }
  }
}

// ---------------------------------------------------------------------------
// relpre via MFMA (combined): bx<96 -> mode0 (wq=bx): C[48 hq][96 wk] vs rel_w
//                             bx>=96 -> mode1 (hq=bx-96): C[96 wq][48 hk] vs rel_h
// ---------------------------------------------------------------------------
__global__ __launch_bounds__(256) void relpre_mfma(
    const unsigned short* __restrict__ qb,
    const float* __restrict__ rel_h, const float* __restrict__ rel_w,
    float* __restrict__ RW, float* __restrict__ RH)
{
  __shared__ __align__(16) unsigned char sm[36864];
  int bxr = (int)blockIdx.x;
  const int mode = bxr >= 96;
  const int bx = mode ? bxr - 96 : bxr;
  const int h = (int)blockIdx.y;
  const int tid = (int)threadIdx.x;
  const int wv = tid >> 6, g = (tid >> 4) & 3, c = tid & 15;
  const int NA = mode ? 96 : 48;
  const int NB = mode ? 48 : 96;
  const int TC = NB >> 4;
  const int roff = mode ? (47 - bx) : (95 - bx);
  const float* rel = mode ? rel_h : rel_w;
  float* outp = mode ? RH : RW;
  unsigned char* const smQ = sm;
  unsigned char* const smR = sm + NA * 256;

  for (int ch = tid; ch < (NA + NB) * 16; ch += 256) {
    if (ch < NA * 16) {
      int i = ch >> 4, d8 = ch & 15;
      int p = mode ? (bx * 96 + i) : (i * 96 + bx);
      s16x8 v = *(const s16x8*)(qb + ((size_t)h * HW_N + p) * 128 + d8 * 8);
      *(s16x8*)(smQ + i * 256 + ((d8 * 16) ^ ((i & 7) << 4))) = v;
    } else {
      int c2 = ch - NA * 16;
      int j = c2 >> 4, d8 = c2 & 15;
      const float* rp = rel + (roff + j) * 128 + d8 * 8;
      f32x4 r0 = *(const f32x4*)(rp);
      f32x4 r1 = *(const f32x4*)(rp + 4);
      s16x8 pk;
#pragma unroll
      for (int e = 0; e < 4; ++e) {
        pk[e] = (short)f2bf(r0[e]);
        pk[4 + e] = (short)f2bf(r1[e]);
      }
      *(s16x8*)(smR + j * 256 + ((d8 * 16) ^ ((j & 7) << 4))) = pk;
    }
  }
  __syncthreads();

  const int swzc = (c & 7) << 4;
  for (int tile = wv; tile < 18; tile += 4) {
    const int tr = tile / TC, tc = tile % TC;
    f32x4 acc = {};
#pragma unroll
    for (int kk = 0; kk < 4; ++kk) {
      const int koff = (kk * 64 + g * 16) ^ swzc;
      s16x8 a = *(const s16x8*)(smQ + (tr * 16 + c) * 256 + koff);
      s16x8 b = *(const s16x8*)(smR + (tc * 16 + c) * 256 + koff);
      acc = __builtin_amdgcn_mfma_f32_16x16x32_bf16(a, b, acc, 0, 0, 0);
    }
#pragma unroll
    for (int j = 0; j < 4; ++j) {
      int i = tr * 16 + g * 4 + j;
      int n = tc * 16 + c;
      if (mode == 0)
        outp[((size_t)h * HW_N + i * 96 + bx) * 96 + n] = acc[j];
      else
        outp[((size_t)h * HW_N + bx * 96 + i) * 48 + n] = acc[j];
    }
  }
}

// ---------------------------------------------------------------------------
// flash attention (round-2 proven body; split-K=6). grid (72,24):
// lin = bx + 72*by; grp = lin%24 -> (h, kh in [0,6)); qt = lin/24.
// block 256 = 4 waves x 16 queries; 16 key-tiles of 48 (image half-rows).
// Unnormalized O (bf16) + (m,l) partials; defer-max THR=8; setprio on MFMA.
// ---------------------------------------------------------------------------
__global__ __launch_bounds__(256, 2) void attn_kernel(
    const unsigned short* __restrict__ qb,
    const unsigned short* __restrict__ kbuf,
    const unsigned short* __restrict__ vbuf,
    const float* __restrict__ RW,
    const float* __restrict__ RH,
    unsigned short* __restrict__ Opart,
    float* __restrict__ mlbuf)
{
  __shared__ __align__(16) unsigned char sm[36864];
  unsigned char* const smK = sm;          // [48 keys][128 d] bf16, swz (row&7)<<4
  unsigned char* const smV = sm + 12288;  // [128 d][64 keyslots] bf16, swz
  unsigned char* const smP = sm + 28672;  // [4 waves][16 q][64 keyslots] bf16

  const int tid = (int)threadIdx.x;
  const int wv = tid >> 6;
  const int g = (tid >> 4) & 3;
  const int c = tid & 15;
  const int swzc = (c & 7) << 4;
  const int pswz_c = ((c >> 2) << 5) | ((c & 1) << 4);

  const int lin = (int)blockIdx.x + 72 * (int)blockIdx.y;
  const int grp = lin % 24, qt = lin / 24;   // 24 ≡ 0 mod 8 -> group pinned to XCD
  const int h = grp & 3, kh = grp >> 2;      // kh in [0,6)

  const int qbase = qt * 64 + wv * 16;
  const int woff = wv * 2048;

  {  // zero P (incl. zero-padded keys 48..63) and V pad columns
    s16x8 z = {};
    *(s16x8*)(smP + tid * 16) = z;
    *(s16x8*)(smP + 4096 + tid * 16) = z;
    int d = tid >> 1, k6 = 6 + (tid & 1);
    *(s16x8*)(smV + d * 128 + ((k6 * 16) ^ ((d & 7) << 4))) = z;
  }

  // Q fragments (A-operand: row = lane&15, k = (lane>>4)*8+e)
  s16x8 aq[4];
  {
    const unsigned short* qrow = qb + ((size_t)h * HW_N + qbase + c) * 128 + g * 8;
#pragma unroll
    for (int kk = 0; kk < 4; ++kk) aq[kk] = *(const s16x8*)(qrow + kk * 32);
  }

  // RW bias registers: per tile-parity [kb][r]; elem = RW[q=g*4+r][wk=par*48+kb*16+c]
  float bw0[3][4], bw1[3][4];
#pragma unroll
  for (int r = 0; r < 4; ++r) {
    const float* rwrow = RW + ((size_t)h * HW_N + qbase + g * 4 + r) * 96 + c;
#pragma unroll
    for (int kb = 0; kb < 3; ++kb) {
      bw0[kb][r] = rwrow[kb * 16];
      bw1[kb][r] = rwrow[48 + kb * 16];
    }
  }
  // RH: the 8 hk values of this kh-sixth live in lanes 0..7 of each group
  float rh_pre[4];
#pragma unroll
  for (int r = 0; r < 4; ++r)
    rh_pre[r] = (c < 8)
        ? RH[((size_t)h * HW_N + qbase + g * 4 + r) * 48 + kh * 8 + c] : 0.f;

  f32x4 o[8];
#pragma unroll
  for (int cb = 0; cb < 8; ++cb) o[cb] = {};
  float mrun[4], lrun[4];
#pragma unroll
  for (int r = 0; r < 4; ++r) { mrun[r] = -1e30f; lrun[r] = 0.f; }

  const unsigned short* kbase = kbuf + ((size_t)h * HW_N + kh * 768) * 128;
  const unsigned short* vbase = vbuf + (size_t)h * 128 * HW_N + kh * 768;

  // staging constants
  const int kkey = tid >> 4, kd8 = tid & 15;
  const int swzk = (kkey & 7) << 4;
  const int vd0 = tid / 6, vk0 = tid % 6;
  const int vd1 = (tid + 256) / 6, vk1 = (tid + 256) % 6;
  const int vd2 = (tid + 512) / 6, vk2 = (tid + 512) % 6;

  s16x8 sK0, sK1, sK2, sV0, sV1, sV2;
  {  // prologue: prefetch tile 0
    const unsigned short* kp = kbase + kkey * 128 + kd8 * 8;
    sK0 = *(const s16x8*)(kp);
    sK1 = *(const s16x8*)(kp + 16 * 128);
    sK2 = *(const s16x8*)(kp + 32 * 128);
    sV0 = *(const s16x8*)(vbase + vd0 * HW_N + vk0 * 8);
    sV1 = *(const s16x8*)(vbase + vd1 * HW_N + vk1 * 8);
    sV2 = *(const s16x8*)(vbase + vd2 * HW_N + vk2 * 8);
  }

  for (int t = 0; t < 16; ++t) {
    __syncthreads();  // all waves done reading previous tile
    *(s16x8*)(smK + kkey * 256 + ((kd8 * 16) ^ swzk)) = sK0;
    *(s16x8*)(smK + (kkey + 16) * 256 + ((kd8 * 16) ^ swzk)) = sK1;
    *(s16x8*)(smK + (kkey + 32) * 256 + ((kd8 * 16) ^ swzk)) = sK2;
    *(s16x8*)(smV + vd0 * 128 + ((vk0 * 16) ^ ((vd0 & 7) << 4))) = sV0;
    *(s16x8*)(smV + vd1 * 128 + ((vk1 * 16) ^ ((vd1 & 7) << 4))) = sV1;
    *(s16x8*)(smV + vd2 * 128 + ((vk2 * 16) ^ ((vd2 & 7) << 4))) = sV2;
    if (t < 15) {  // prefetch next tile
      int j0n = (t + 1) * 48;
      const unsigned short* kp = kbase + (j0n + kkey) * 128 + kd8 * 8;
      sK0 = *(const s16x8*)(kp);
      sK1 = *(const s16x8*)(kp + 16 * 128);
      sK2 = *(const s16x8*)(kp + 32 * 128);
      sV0 = *(const s16x8*)(vbase + vd0 * HW_N + j0n + vk0 * 8);
      sV1 = *(const s16x8*)(vbase + vd1 * HW_N + j0n + vk1 * 8);
      sV2 = *(const s16x8*)(vbase + vd2 * HW_N + j0n + vk2 * 8);
    }
    float rh_[4];
    {
      const int hkl = t >> 1;
#pragma unroll
      for (int r = 0; r < 4; ++r) rh_[r] = __shfl(rh_pre[r], hkl, 16);
    }
    __syncthreads();  // staged tile visible

    // ---- S = Q K^T (16q x 48k) ----
    f32x4 s0 = {}, s1 = {}, s2 = {};
    __builtin_amdgcn_s_setprio(1);
#pragma unroll
    for (int kk = 0; kk < 4; ++kk) {
      const int inr = kk * 64 + g * 16;
      s16x8 b0 = *(const s16x8*)(smK + c * 256 + (inr ^ swzc));
      s16x8 b1 = *(const s16x8*)(smK + (16 + c) * 256 + (inr ^ swzc));
      s16x8 b2 = *(const s16x8*)(smK + (32 + c) * 256 + (inr ^ swzc));
      s0 = __builtin_amdgcn_mfma_f32_16x16x32_bf16(aq[kk], b0, s0, 0, 0, 0);
      s1 = __builtin_amdgcn_mfma_f32_16x16x32_bf16(aq[kk], b1, s1, 0, 0, 0);
      s2 = __builtin_amdgcn_mfma_f32_16x16x32_bf16(aq[kk], b2, s2, 0, 0, 0);
    }
    __builtin_amdgcn_s_setprio(0);

    // ---- bias + online softmax with defer-max ----
    const bool par = (t & 1) != 0;
    float x0[4], x1[4], x2[4], tm3[4];
    int need = 0;
#pragma unroll
    for (int r = 0; r < 4; ++r) {
      x0[r] = s0[r] + (par ? bw1[0][r] : bw0[0][r]) + rh_[r];
      x1[r] = s1[r] + (par ? bw1[1][r] : bw0[1][r]) + rh_[r];
      x2[r] = s2[r] + (par ? bw1[2][r] : bw0[2][r]) + rh_[r];
      tm3[r] = fmaxf(fmaxf(x0[r], x1[r]), x2[r]);
      need |= (tm3[r] > mrun[r] + 8.f);
    }
    if (__any(need)) {
#pragma unroll
      for (int r = 0; r < 4; ++r) {
        float tg = tm3[r];
        tg = fmaxf(tg, __shfl_xor(tg, 1, 16));
        tg = fmaxf(tg, __shfl_xor(tg, 2, 16));
        tg = fmaxf(tg, __shfl_xor(tg, 4, 16));
        tg = fmaxf(tg, __shfl_xor(tg, 8, 16));
        float mn = fmaxf(mrun[r], tg);
        float fac = __expf(mrun[r] - mn);
        mrun[r] = mn;
        lrun[r] *= fac;
#pragma unroll
        for (int cb = 0; cb < 8; ++cb) o[cb][r] *= fac;
      }
    }
#pragma unroll
    for (int r = 0; r < 4; ++r) {
      float p0 = __expf(x0[r] - mrun[r]);
      float p1 = __expf(x1[r] - mrun[r]);
      float p2 = __expf(x2[r] - mrun[r]);
      lrun[r] += p0 + p1 + p2;
      const int q_ = g * 4 + r;
      unsigned char* prow = smP + woff + q_ * 128;
      const int swzq = ((q_ >> 2) << 5) | ((q_ & 1) << 4);
      *(unsigned short*)(prow + ((c * 2) ^ swzq)) = f2bf(p0);
      *(unsigned short*)(prow + ((32 + c * 2) ^ swzq)) = f2bf(p1);
      *(unsigned short*)(prow + ((64 + c * 2) ^ swzq)) = f2bf(p2);
    }

    // ---- O += P V ----
    s16x8 pa0 = *(const s16x8*)(smP + woff + c * 128 + ((g * 16) ^ pswz_c));
    s16x8 pa1 = *(const s16x8*)(smP + woff + c * 128 + ((64 + g * 16) ^ pswz_c));
    __builtin_amdgcn_s_setprio(1);
#pragma unroll
    for (int cb = 0; cb < 8; ++cb) {
      const unsigned char* vrow = smV + (cb * 16 + c) * 128;
      s16x8 v0 = *(const s16x8*)(vrow + ((g * 16) ^ swzc));
      s16x8 v1 = *(const s16x8*)(vrow + ((64 + g * 16) ^ swzc));
      o[cb] = __builtin_amdgcn_mfma_f32_16x16x32_bf16(pa0, v0, o[cb], 0, 0, 0);
      o[cb] = __builtin_amdgcn_mfma_f32_16x16x32_bf16(pa1, v1, o[cb], 0, 0, 0);
    }
    __builtin_amdgcn_s_setprio(0);
  }

  // final per-row l reduce across the 16-lane group
#pragma unroll
  for (int r = 0; r < 4; ++r) {
    lrun[r] += __shfl_xor(lrun[r], 1, 16);
    lrun[r] += __shfl_xor(lrun[r], 2, 16);
    lrun[r] += __shfl_xor(lrun[r], 4, 16);
    lrun[r] += __shfl_xor(lrun[r], 8, 16);
  }

  const int pb = (kh * 4 + h) * HW_N;
#pragma unroll
  for (int r = 0; r < 4; ++r) {
    const int p = qbase + g * 4 + r;
    unsigned short* orow = Opart + ((size_t)pb + p) * 128 + c;
#pragma unroll
    for (int cb = 0; cb < 8; ++cb) orow[cb * 16] = f2bf(o[cb][r]);
    if (c == 0) {
      mlbuf[((size_t)pb + p) * 2 + 0] = mrun[r];
      mlbuf[((size_t)pb + p) * 2 + 1] = lrun[r];
    }
  }
}

// ---------------------------------------------------------------------------
// merge 6 split-K partials -> oatt[p][512] bf16 (p-major)
// ---------------------------------------------------------------------------
__global__ __launch_bounds__(256) void merge_kernel(
    const unsigned short* __restrict__ Opart, const float* __restrict__ mlbuf,
    unsigned short* __restrict__ oatt)
{
  int idx = (int)blockIdx.x * 256 + (int)threadIdx.x;  // 4*4608*32
  int d4 = idx & 31;
  int rest = idx >> 5;
  int p = rest % HW_N;
  int h = rest / HW_N;
  float m[6], lv[6];
#pragma unroll
  for (int s = 0; s < 6; ++s) {
    int ip = (s * 4 + h) * HW_N + p;
    m[s] = mlbuf[(size_t)ip * 2];
    lv[s] = mlbuf[(size_t)ip * 2 + 1];
  }
  float M = m[0];
#pragma unroll
  for (int s = 1; s < 6; ++s) M = fmaxf(M, m[s]);
  float a[6], den = 0.f;
#pragma unroll
  for (int s = 0; s < 6; ++s) { a[s] = __expf(m[s] - M); den += a[s] * lv[s]; }
  float rd = 1.f / den;
  f32x4 acc = {};
#pragma unroll
  for (int s = 0; s < 6; ++s) {
    int ip = (s * 4 + h) * HW_N + p;
    u16x4 ov = *(const u16x4*)(Opart + (size_t)ip * 128 + d4 * 4);
#pragma unroll
    for (int j = 0; j < 4; ++j) acc[j] = fmaf(a[s], bf2f(ov[j]), acc[j]);
  }
  u16x4 res;
#pragma unroll
  for (int j = 0; j < 4; ++j) res[j] = f2bf(acc[j] * rd);
  *(u16x4*)(oatt + (size_t)p * 512 + h * 128 + d4 * 4) = res;
}

// ---------------------------------------------------------------------------
// convout (MFMA): fm[p][256] bf16 = relu(bn(w_out @ oatt^T) + x); K=512
// grid (36, 4): C tile [64 oc][128 p]
// ---------------------------------------------------------------------------
__global__ __launch_bounds__(256) void convout_kernel(
    const unsigned short* __restrict__ oatt, const float* __restrict__ w,
    const float* __restrict__ gg, const float* __restrict__ bb,
    const float* __restrict__ mm, const float* __restrict__ vv,
    const float* __restrict__ x, unsigned short* __restrict__ fm)
{
  __shared__ __align__(16) unsigned char smA[8192];   // [64 oc][64 cc] bf16 swz
  __shared__ __align__(16) unsigned char smB[16384];  // [128 p][64 cc] bf16 swz
  const int tid = (int)threadIdx.x;
  const int wv = tid >> 6, g = (tid >> 4) & 3, c = tid & 15;
  const int p0 = (int)blockIdx.x * 128;
  const int o0 = (int)blockIdx.y * 64;
  const int swzc = (c & 7) << 4;
  const int aoc = tid >> 2, aq4 = tid & 3;
  const int brow = tid >> 3, bcol = (tid & 7) * 16;
  f32x4 acc[8];
#pragma unroll
  for (int cb = 0; cb < 8; ++cb) acc[cb] = {};

  for (int ch = 0; ch < 8; ++ch) {
    __syncthreads();
#pragma unroll
    for (int i = 0; i < 4; ++i)
      gload_lds16((const char*)oatt + (size_t)(p0 + i * 32 + brow) * 1024 + ch * 128 +
                      (bcol ^ ((brow & 7) << 4)),
                  smB + i * 4096 + wv * 1024);
    {
      const float* wp = w + (size_t)(o0 + aoc) * 512 + ch * 64 + aq4 * 16;
      f32x4 a0 = *(const f32x4*)(wp);
      f32x4 a1 = *(const f32x4*)(wp + 4);
      f32x4 a2 = *(const f32x4*)(wp + 8);
      f32x4 a3 = *(const f32x4*)(wp + 12);
      s16x8 w0, w1;
#pragma unroll
      for (int e = 0; e < 4; ++e) {
        w0[e] = (short)f2bf(a0[e]); w0[4 + e] = (short)f2bf(a1[e]);
        w1[e] = (short)f2bf(a2[e]); w1[4 + e] = (short)f2bf(a3[e]);
      }
      *(s16x8*)(smA + aoc * 128 + ((aq4 * 32) ^ ((aoc & 7) << 4))) = w0;
      *(s16x8*)(smA + aoc * 128 + ((aq4 * 32 + 16) ^ ((aoc & 7) << 4))) = w1;
    }
    __syncthreads();
#pragma unroll
    for (int kk = 0; kk < 2; ++kk) {
      s16x8 a = *(const s16x8*)(smA + (wv * 16 + c) * 128 + ((kk * 64 + g * 16) ^ swzc));
#pragma unroll
      for (int cb = 0; cb < 8; ++cb) {
        s16x8 b = *(const s16x8*)(smB + (cb * 16 + c) * 128 + ((kk * 64 + g * 16) ^ swzc));
        acc[cb] = __builtin_amdgcn_mfma_f32_16x16x32_bf16(a, b, acc[cb], 0, 0, 0);
      }
    }
  }

  __syncthreads();
  float inv[4], bia[4];
#pragma unroll
  for (int r = 0; r < 4; ++r) {
    int oc = o0 + wv * 16 + g * 4 + r;
    inv[r] = gg[oc] * rsqrtf(vv[oc] + EPS);
    bia[r] = bb[oc] - mm[oc] * inv[r];
  }
#pragma unroll
  for (int cb = 0; cb < 8; ++cb)
#pragma unroll
    for (int r = 0; r < 4; ++r) {
      int oc = o0 + wv * 16 + g * 4 + r;
      int p = p0 + cb * 16 + c;
      float v = fmaxf(acc[cb][r] * inv[r] + bia[r] + x[(size_t)oc * HW_N + p], 0.f);
      *(unsigned short*)(smB + (cb * 16 + c) * 128 +
                         (((wv * 16 + g * 4 + r) * 2) ^ swzc)) = f2bf(v);
    }
  __syncthreads();
#pragma unroll
  for (int i = 0; i < 4; ++i) {
    int row = i * 32 + brow;
    s16x8 vd = *(const s16x8*)(smB + row * 128 + (bcol ^ ((row & 7) << 4)));
    *(s16x8*)((char*)fm + (size_t)(p0 + row) * 512 + o0 * 2 + bcol) = vd;
  }
}

// ---------------------------------------------------------------------------
// convhead (MFMA): out[19][4608] = w_head @ fm^T + b_head; K=256. grid 36.
// ---------------------------------------------------------------------------
__global__ __launch_bounds__(256) void convhead_kernel(
    const unsigned short* __restrict__ fm, const float* __restrict__ w,
    const float* __restrict__ bh, float* __restrict__ outp)
{
  __shared__ __align__(16) unsigned char smA[4096];   // [32 oc][64 cc] bf16 swz
  __shared__ __align__(16) unsigned char smB[16384];  // [128 p][64 cc] bf16 swz
  const int tid = (int)threadIdx.x;
  const int wv = tid >> 6, g = (tid >> 4) & 3, c = tid & 15;
  const int p0 = (int)blockIdx.x * 128;
  const int swzc = (c & 7) << 4;
  const int aoc = tid >> 3, aq8 = tid & 7;
  const int brow = tid >> 3, bcol = (tid & 7) * 16;
  f32x4 acc[2][2];
#pragma unroll
  for (int u = 0; u < 2; ++u)
#pragma unroll
    for (int cbi = 0; cbi < 2; ++cbi) acc[u][cbi] = {};

  for (int ch = 0; ch < 4; ++ch) {
    __syncthreads();
#pragma unroll
    for (int i = 0; i < 4; ++i)
      gload_lds16((const char*)fm + (size_t)(p0 + i * 32 + brow) * 512 + ch * 128 +
                      (bcol ^ ((brow & 7) << 4)),
                  smB + i * 4096 + wv * 1024);
    {
      s16x8 w0 = {};
      if (aoc < 19) {
        const float* wp = w + (size_t)aoc * 256 + ch * 64 + aq8 * 8;
        f32x4 a0 = *(const f32x4*)(wp);
        f32x4 a1 = *(const f32x4*)(wp + 4);
#pragma unroll
        for (int e = 0; e < 4; ++e) {
          w0[e] = (short)f2bf(a0[e]);
          w0[4 + e] = (short)f2bf(a1[e]);
        }
      }
      *(s16x8*)(smA + aoc * 128 + ((aq8 * 16) ^ ((aoc & 7) << 4))) = w0;
    }
    __syncthreads();
#pragma unroll
    for (int kk = 0; kk < 2; ++kk) {
      s16x8 a0 = *(const s16x8*)(smA + c * 128 + ((kk * 64 + g * 16) ^ swzc));
      s16x8 a1 = *(const s16x8*)(smA + (16 + c) * 128 + ((kk * 64 + g * 16) ^ swzc));
#pragma unroll
      for (int cbi = 0; cbi < 2; ++cbi) {
        int cb = wv * 2 + cbi;
        s16x8 b = *(const s16x8*)(smB + (cb * 16 + c) * 128 + ((kk * 64 + g * 16) ^ swzc));
        acc[0][cbi] = __builtin_amdgcn_mfma_f32_16x16x32_bf16(a0, b, acc[0][cbi], 0, 0, 0);
        acc[1][cbi] = __builtin_amdgcn_mfma_f32_16x16x32_bf16(a1, b, acc[1][cbi], 0, 0, 0);
      }
    }
  }
#pragma unroll
  for (int u = 0; u < 2; ++u)
#pragma unroll
    for (int cbi = 0; cbi < 2; ++cbi)
#pragma unroll
      for (int r = 0; r < 4; ++r) {
        int oc = u * 16 + g * 4 + r;
        if (oc < 19) {
          int p = p0 + (wv * 2 + cbi) * 16 + c;
          outp[(size_t)oc * HW_N + p] = acc[u][cbi][r] + bh[oc];
        }
      }
}

// ---------------------------------------------------------------------------
extern "C" void kernel_launch(void* const* d_in, const int* in_sizes, int n_in,
                              void* d_out, int out_size, void* d_ws, size_t ws_size,
                              hipStream_t stream)
{
  const float* x     = (const float*)d_in[0];
  const float* w_in  = (const float*)d_in[1];
  const float* bn1_g = (const float*)d_in[2];
  const float* bn1_b = (const float*)d_in[3];
  const float* bn1_m = (const float*)d_in[4];
  const float* bn1_v = (const float*)d_in[5];
  const float* w_qkv = (const float*)d_in[6];
  const float* rel_h = (const float*)d_in[7];
  const float* rel_w = (const float*)d_in[8];
  const float* w_out = (const float*)d_in[9];
  const float* bn2_g = (const float*)d_in[10];
  const float* bn2_b = (const float*)d_in[11];
  const float* bn2_m = (const float*)d_in[12];
  const float* bn2_v = (const float*)d_in[13];
  const float* w_hd  = (const float*)d_in[14];
  const float* b_hd  = (const float*)d_in[15];

  char* ws = (char*)d_ws;
  float*          h1    = (float*)(ws + 0);                   // 1,179,648 B
  float*          mlb   = (float*)(ws + 0);                   // 884,736 B (h1 dead)
  unsigned short* qb    = (unsigned short*)(ws + 1179648);    // 4,718,592 B
  unsigned short* kb    = (unsigned short*)(ws + 5898240);    // 4,718,592 B
  unsigned short* vb    = (unsigned short*)(ws + 10616832);   // 4,718,592 B
  float*          RW    = (float*)(ws + 15335424);            // 7,077,888 B
  float*          RH    = (float*)(ws + 22413312);            // 3,538,944 B
  unsigned short* oatt  = (unsigned short*)(ws + 15335424);   // 4,718,592 B (over dead RW)
  unsigned short* fm    = (unsigned short*)(ws + 20054016);   // 2,359,296 B (over dead RW/RH)
  unsigned short* Opart = (unsigned short*)(ws + 25952256);   // 28,311,552 B (24 partials bf16)

  conv1_kernel<<<72, 256, 0, stream>>>(x, w_in, bn1_g, bn1_b, bn1_m, bn1_v, h1);
  convqkv_kernel<<<dim3(72, 24), 256, 0, stream>>>(h1, w_qkv, qb, kb, vb);
  relpre_mfma<<<dim3(144, 4), 256, 0, stream>>>(qb, rel_h, rel_w, RW, RH);
  attn_kernel<<<dim3(72, 24), 256, 0, stream>>>(qb, kb, vb, RW, RH, Opart, mlb);
  merge_kernel<<<2304, 256, 0, stream>>>(Opart, mlb, oatt);
  convout_kernel<<<dim3(36, 4), 256, 0, stream>>>(oatt, w_out, bn2_g, bn2_b, bn2_m,
                                                  bn2_v, x, fm);
  convhead_kernel<<<36, 256, 0, stream>>>(fm, w_hd, b_hd, (float*)d_out);
}